// Round 8
// baseline (308.959 us; speedup 1.0000x reference)
//
#include <hip/hip_runtime.h>
#include <hip/hip_bf16.h>
#include <cstdint>
#include <cstddef>

#define B_ 4
#define S_ 2048
#define E_ 1024
#define H_ 16
#define D_ 64
#define NEG_BIG (-1e30f)
#define SC2 0.18033688011112043f   /* 0.125 * log2(e) */

typedef __bf16 bf16x8 __attribute__((ext_vector_type(8)));
typedef __bf16 bf16x4v __attribute__((ext_vector_type(4)));
typedef float f32x4 __attribute__((ext_vector_type(4)));
typedef float f32x16 __attribute__((ext_vector_type(16)));

__device__ __forceinline__ void async_copy16(void* lds, const void* g) {
  __builtin_amdgcn_global_load_lds(
      (const __attribute__((address_space(1))) void*)g,
      (__attribute__((address_space(3))) void*)lds, 16, 0, 0);
}

__device__ __forceinline__ float bfu2f(unsigned short u) {
  unsigned v = ((unsigned)u) << 16;
  float f;
  __builtin_memcpy(&f, &v, 4);
  return f;
}
__device__ __forceinline__ unsigned short f2bfu(float f) {
  __hip_bfloat16 h = __float2bfloat16(f);  // RNE
  unsigned short u;
  __builtin_memcpy(&u, &h, 2);
  return u;
}
__device__ __forceinline__ unsigned pk2(float a, float b) {
  return (unsigned)f2bfu(a) | ((unsigned)f2bfu(b) << 16);
}

// swap hi 32 lanes of a with lo 32 lanes of b (v_permlane32_swap_b32)
__device__ __forceinline__ void pl32swap(unsigned& a, unsigned& b) {
#if defined(__has_builtin)
#if __has_builtin(__builtin_amdgcn_permlane32_swap)
  typedef int i32x2 __attribute__((ext_vector_type(2)));
  i32x2 r = __builtin_amdgcn_permlane32_swap((int)a, (int)b, false, false);
  a = (unsigned)r[0];
  b = (unsigned)r[1];
  return;
#else
  asm("v_permlane32_swap_b32 %0, %1" : "+v"(a), "+v"(b));
  return;
#endif
#else
  asm("v_permlane32_swap_b32 %0, %1" : "+v"(a), "+v"(b));
#endif
}

// ---------------- dtype probe (proven) ----------------
__global__ __launch_bounds__(256) void probe_dtype(
    const unsigned short* __restrict__ xr, int* __restrict__ flagp) {
  __shared__ int cnt;
  if (threadIdx.x == 0) cnt = 0;
  __syncthreads();
  int bad = 0;
  for (int i = 0; i < 32; ++i) {
    unsigned short u = xr[(threadIdx.x * 32 + i) * 2];
    int e = (u >> 7) & 0xFF;
    if (e == 0xFF || e >= 0x90 || (e != 0 && e <= 0x60)) bad++;
  }
  atomicAdd(&cnt, bad);
  __syncthreads();
  if (threadIdx.x == 0) {
    flagp[0] = (cnt > 512) ? 0 : 1;  // 0=fp32, 1=bf16
    flagp[1] = 1;                    // all-ones-mask flag, cleared by prep
  }
}

// fused preamble: mask->bias (+allones detect), bias_qkv/bias_proj -> f32
__global__ __launch_bounds__(256) void prep(
    const int* __restrict__ am, float* __restrict__ mb,
    int* __restrict__ flagp,
    const void* __restrict__ bq_in, float* __restrict__ bq,
    const void* __restrict__ bp_in, float* __restrict__ bp) {
  int i = blockIdx.x * 256 + threadIdx.x;
  const int flag = flagp[0];
  if (i < 8192) {
    int a = am[i];
    mb[i] = a ? 0.f : NEG_BIG;
    if (a == 0) atomicAnd(flagp + 1, 0);
  } else if (i < 11264) {
    int j = i - 8192;
    bq[j] = (flag == 0) ? ((const float*)bq_in)[j]
                        : bfu2f(((const unsigned short*)bq_in)[j]);
  } else if (i < 12288) {
    int j = i - 11264;
    bp[j] = (flag == 0) ? ((const float*)bp_in)[j]
                        : bfu2f(((const unsigned short*)bp_in)[j]);
  }
}

// x (fp32|bf16) -> bf16, vectorized 8 elems/thread
__global__ __launch_bounds__(256) void conv_x_bf16(
    const void* __restrict__ in, long long off,
    unsigned short* __restrict__ out,
    const int* __restrict__ flagp, int n8) {
  int i = blockIdx.x * 256 + threadIdx.x;
  if (i >= n8) return;
  if (*flagp == 0) {
    const float* p = (const float*)in + off + (size_t)i * 8;
    float4 a = *(const float4*)p;
    float4 b = *(const float4*)(p + 4);
    uint4 o = make_uint4(pk2(a.x, a.y), pk2(a.z, a.w), pk2(b.x, b.y), pk2(b.z, b.w));
    *(uint4*)(out + (size_t)i * 8) = o;
  } else {
    const unsigned short* p = (const unsigned short*)in + off + (size_t)i * 8;
    *(uint4*)(out + (size_t)i * 8) = *(const uint4*)p;
  }
}

// transpose + convert: out_bf16[C][R] = in[R][C]   (proven)
__global__ __launch_bounds__(256) void transpose_conv(
    const void* __restrict__ in, unsigned short* __restrict__ out,
    const int* __restrict__ flagp, int R, int C) {
  __shared__ unsigned short t[32][33];
  const int flag = *flagp;
  const int c0 = blockIdx.x * 32, r0 = blockIdx.y * 32;
  const int lc = threadIdx.x & 31, lr = threadIdx.x >> 5;
  for (int i = 0; i < 4; ++i) {
    int r = lr + i * 8;
    size_t idx = (size_t)(r0 + r) * C + c0 + lc;
    t[r][lc] = (flag == 0) ? f2bfu(((const float*)in)[idx])
                           : ((const unsigned short*)in)[idx];
  }
  __syncthreads();
  for (int i = 0; i < 4; ++i) {
    int r = lr + i * 8;
    out[(size_t)(c0 + r) * R + r0 + lc] = t[lc][r];
  }
}

// -------- unified bf16 GEMM (R6-proven): C = A @ Bt^T + bias -------------
// 128x128 tile, 256 threads, BK=64 (32 MFMA per barrier pair), async
// global->LDS, 8-chunk XOR swizzle (ch ^ row&7), XCD-chunked 1D grid.
// bf16 out: staged through dead 32KB LDS, coalesced dwordx4 writes.
// fp32 out: direct scalar stores.  (R7's 256x128 dbuf variant was NULL:
// 96KB LDS -> 1 block/CU traded away the TLP that was hiding staging.)
__global__ __launch_bounds__(256) void gemm_bb(
    const __hip_bfloat16* __restrict__ A,
    const __hip_bfloat16* __restrict__ Bt,
    const float* __restrict__ bias,
    const int* __restrict__ flagp, int outmode,
    void* __restrict__ Cv, long long coff,
    int M, int N, int K) {
  __shared__ __align__(16) __hip_bfloat16 SH[2][128 * 64];
  __hip_bfloat16* As = SH[0];
  __hip_bfloat16* Bs = SH[1];
  const int flag = *flagp;
  const int tid = threadIdx.x;
  const int lin = blockIdx.x;
  const int mtiles = M >> 7;
  const int mloc = mtiles >> 3;                 // m-tiles per XCD (pow2)
  const int msh = 31 - __builtin_clz(mloc);
  const int xcd = lin & 7, idx = lin >> 3;
  const int m0 = (xcd * mloc + (idx & (mloc - 1))) << 7;
  const int n0 = (idx >> msh) << 7;
  const int w = tid >> 6, lane = tid & 63;
  const int wm = (w & 1) * 64, wn = (w >> 1) * 64;
  const int lm = lane & 15, kg = lane >> 4;

  f32x4 acc[4][4] = {};

  for (int k0 = 0; k0 < K; k0 += 64) {
    __syncthreads();   // readers of LDS done
    #pragma unroll
    for (int c = 0; c < 4; ++c) {
      int o = tid * 16 + c * 4096;
      int row = o >> 7, chp = (o >> 4) & 7;
      int gch = chp ^ (row & 7);
      async_copy16((char*)As + o, (const char*)(A + (size_t)(m0 + row) * K + k0 + gch * 8));
      async_copy16((char*)Bs + o, (const char*)(Bt + (size_t)(n0 + row) * K + k0 + gch * 8));
    }
    __syncthreads();   // staging landed (compiler drains vmcnt before barrier)
    #pragma unroll
    for (int kk = 0; kk < 2; ++kk) {
      bf16x8 af[4], bff[4];
      #pragma unroll
      for (int t = 0; t < 4; ++t) {
        int rt = wm + t * 16 + lm;
        int ch = (kk * 4 + kg) ^ (rt & 7);
        af[t] = *(const bf16x8*)(As + rt * 64 + ch * 8);
        int rb = wn + t * 16 + lm;
        int chb = (kk * 4 + kg) ^ (rb & 7);
        bff[t] = *(const bf16x8*)(Bs + rb * 64 + chb * 8);
      }
      #pragma unroll
      for (int tm = 0; tm < 4; ++tm)
        #pragma unroll
        for (int tn = 0; tn < 4; ++tn)
          acc[tm][tn] = __builtin_amdgcn_mfma_f32_16x16x32_bf16(af[tm], bff[tn], acc[tm][tn], 0, 0, 0);
    }
  }

  const bool f32out = (outmode != 0 && flag == 0);
  if (f32out) {
    // direct scalar stores (proven) -- f32 tile doesn't fit staged in LDS
    for (int tn = 0; tn < 4; ++tn) {
      int col = n0 + wn + tn * 16 + lm;
      float bv = bias[col];
      for (int tm = 0; tm < 4; ++tm) {
        int rbase = m0 + wm + tm * 16 + kg * 4;
        for (int r = 0; r < 4; ++r)
          ((float*)Cv)[(size_t)coff + (size_t)(rbase + r) * N + col] =
              acc[tm][tn][r] + bv;
      }
    }
  } else {
    // bf16: LDS-staged coalesced writes, two 64-row passes (stride 136>127)
    for (int hp = 0; hp < 2; ++hp) {
      __syncthreads();   // prior LDS readers done
      if (wm == hp * 64) {
        __hip_bfloat16* Cs16 = (__hip_bfloat16*)SH;  // stride 136 (272B)
        #pragma unroll
        for (int tn = 0; tn < 4; ++tn) {
          int col = wn + tn * 16 + lm;
          float bv = bias[n0 + col];
          #pragma unroll
          for (int tm = 0; tm < 4; ++tm)
            #pragma unroll
            for (int r = 0; r < 4; ++r)
              Cs16[(tm * 16 + kg * 4 + r) * 136 + col] =
                  __float2bfloat16(acc[tm][tn][r] + bv);
        }
      }
      __syncthreads();
      const __hip_bfloat16* Cs16 = (const __hip_bfloat16*)SH;
      unsigned short* outp = (unsigned short*)Cv + coff;
      #pragma unroll
      for (int rd = 0; rd < 4; ++rd) {
        int chunk = rd * 256 + tid;             // 0..1023
        int row = chunk >> 4, cch = chunk & 15;
        uint4 v = *(const uint4*)(Cs16 + row * 136 + cch * 8);
        *(uint4*)(outp + (size_t)(m0 + hp * 64 + row) * N + n0 + cch * 8) = v;
      }
    }
  }
}

// -------- causal flash attention v7: paired q-tiles ------------------------
// 256 threads (4 waves), 32-key subtiles, K direct global->VGPR pipelined,
// V via double-buffered LDS (proven v5 body).  NEW: each block processes
// TWO q-tiles -- pr (light) then 15-pr (heavy) -- so per-block work is
// exactly uniform (34 key-tile units).  512 blocks = 2/CU, constant
// 8 waves/CU for the whole kernel: kills the 80-vs-56-unit per-CU work
// imbalance + end-of-kernel TLP collapse that capped v5 at 27% occupancy.
// Light tile first: its K/V prefix warms L2 for the heavy pass.
// NOTE: do NOT shrink blocks / raise launch_bounds min-waves: the 128-thread
// (128,4) variant spilled (~470 MB scratch writes, 2.5x slower).
#define VSTR 72
__device__ __forceinline__ void attn_subtile(
    int j0s, int wq_min, int wq_max, int qg, int allones,
    const char* kbyte, const float* mbrow,
    uint4& kc0, uint4& kc1, uint4& kc2, uint4& kc3,
    uint4& kn0, uint4& kn1, uint4& kn2, uint4& kn3,
    const bf16x8* bq, const __hip_bfloat16* VTb, int hi,
    float& mrow, float& plocal, f32x16& o0, f32x16& o1) {
  if (j0s > wq_max) return;
  {  // prefetch next subtile's K fragments (registers)
    const int jn = j0s + 32;
    if (jn <= wq_max) {
      const char* kp = kbyte + (size_t)jn * 6144;
      kn0 = *(const uint4*)(kp);
      kn1 = *(const uint4*)(kp + 32);
      kn2 = *(const uint4*)(kp + 64);
      kn3 = *(const uint4*)(kp + 96);
    }
  }
  bf16x8 a0, a1, a2, a3;
  __builtin_memcpy(&a0, &kc0, 16);
  __builtin_memcpy(&a1, &kc1, 16);
  __builtin_memcpy(&a2, &kc2, 16);
  __builtin_memcpy(&a3, &kc3, 16);

  // ---- S^T = K · Q^T ----
  f32x16 sacc = {};
  __builtin_amdgcn_s_setprio(1);
  sacc = __builtin_amdgcn_mfma_f32_32x32x16_bf16(a0, bq[0], sacc, 0, 0, 0);
  sacc = __builtin_amdgcn_mfma_f32_32x32x16_bf16(a1, bq[1], sacc, 0, 0, 0);
  sacc = __builtin_amdgcn_mfma_f32_32x32x16_bf16(a2, bq[2], sacc, 0, 0, 0);
  sacc = __builtin_amdgcn_mfma_f32_32x32x16_bf16(a3, bq[3], sacc, 0, 0, 0);
  __builtin_amdgcn_s_setprio(0);

  // ---- mask + max ----
  float mt = NEG_BIG;
  const bool needc = (j0s + 31 > wq_min);
  if (allones) {
    if (needc) {
      #pragma unroll
      for (int r = 0; r < 16; ++r) {
        int key = j0s + (r & 3) + 8 * (r >> 2) + 4 * hi;
        float v = (key <= qg) ? sacc[r] : NEG_BIG;
        sacc[r] = v;
        mt = fmaxf(mt, v);
      }
    } else {
      #pragma unroll
      for (int r = 0; r < 16; ++r) mt = fmaxf(mt, sacc[r]);
    }
    mt *= SC2;  // scores stay raw; scale folded into exp fma
  } else {
    #pragma unroll
    for (int rr = 0; rr < 4; ++rr) {
      float4 mb4 = *(const float4*)(mbrow + j0s + rr * 8 + hi * 4);
      const float* mp = (const float*)&mb4;
      #pragma unroll
      for (int i = 0; i < 4; ++i) {
        int r = rr * 4 + i;
        int key = j0s + i + 8 * rr + 4 * hi;
        float v = fmaf(sacc[r], SC2, mp[i]);
        if (needc) v = (key <= qg) ? v : NEG_BIG;
        sacc[r] = v;
        mt = fmaxf(mt, v);
      }
    }
  }
  mt = fmaxf(mt, __shfl_xor(mt, 32));

  // ---- defer-max rescale (THR=8, log2 domain) ----
  if (!__all(mt <= mrow + 8.f)) {
    float mn = fmaxf(mrow, mt);
    float a = __builtin_exp2f(mrow - mn);
    plocal *= a;
    #pragma unroll
    for (int r = 0; r < 16; ++r) { o0[r] *= a; o1[r] *= a; }
    mrow = mn;
  }

  // ---- exp + pack ----
  const float sfac = allones ? SC2 : 1.0f;
  float psl = 0.f;
  unsigned pk[8];
  #pragma unroll
  for (int r2 = 0; r2 < 8; ++r2) {
    float p0 = __builtin_exp2f(fmaf(sacc[2 * r2],     sfac, -mrow));
    float p1 = __builtin_exp2f(fmaf(sacc[2 * r2 + 1], sfac, -mrow));
    psl += p0 + p1;
    pk[r2] = pk2(p0, p1);
  }
  plocal += psl;

  // ---- in-register P exchange ----
  pl32swap(pk[0], pk[2]);
  pl32swap(pk[1], pk[3]);
  pl32swap(pk[4], pk[6]);
  pl32swap(pk[5], pk[7]);

  // ---- O^T += V^T · P ----
  __builtin_amdgcn_s_setprio(1);
  #pragma unroll
  for (int ks = 0; ks < 2; ++ks) {
    uint4 t = make_uint4(pk[ks * 4 + 0], pk[ks * 4 + 1],
                         pk[ks * 4 + 2], pk[ks * 4 + 3]);
    bf16x8 bp;
    __builtin_memcpy(&bp, &t, 16);
    bf16x8 av0 = *(const bf16x8*)(VTb + ks * 16);
    bf16x8 av1 = *(const bf16x8*)(VTb + 32 * VSTR + ks * 16);
    o0 = __builtin_amdgcn_mfma_f32_32x32x16_bf16(av0, bp, o0, 0, 0, 0);
    o1 = __builtin_amdgcn_mfma_f32_32x32x16_bf16(av1, bp, o1, 0, 0, 0);
  }
  __builtin_amdgcn_s_setprio(0);
}

__global__ __launch_bounds__(256, 3) void attn_flash(
    const __hip_bfloat16* __restrict__ qkv,  // [bsz*S][3072]
    const float* __restrict__ mbias,         // [bsz*S] 0 / -1e30
    const int* __restrict__ flags,           // flags[1]: mask all-ones
    __hip_bfloat16* __restrict__ outp) {     // [bsz*S][1024]
  __shared__ __align__(16) __hip_bfloat16 VT[2][64 * VSTR]; // [d][key]

  const int tid = threadIdx.x;
  // XCD-chunked: XCD k owns bh chunk; idx>>bsh selects the q-tile PAIR.
  const int lin = blockIdx.x;
  const int nbh = gridDim.x >> 3;          // 8 q-pairs per bh
  const int bhloc = nbh >> 3;
  const int bsh = 31 - __builtin_clz(bhloc);
  const int xcd = lin & 7, idx = lin >> 3;
  const int bh = xcd * bhloc + (idx & (bhloc - 1));
  const int pr = idx >> bsh;               // 0..7
  const int b = bh >> 4, h = bh & 15;
  const size_t rowbase = (size_t)b * S_;
  const int w = tid >> 6, lane = tid & 63;
  const int l31 = lane & 31, hi = lane >> 5;
  const int allones = flags[1];
  const float* mbrow = mbias + rowbase;

  // per-lane K base: row l31, d-offset hi*8 (fragment kc at +kc*32B)
  const char* kbyte = (const char*)(qkv + (rowbase + l31) * 3072 + 1024 + h * 64 + hi * 8);

  #pragma unroll 1
  for (int pass = 0; pass < 2; ++pass) {
    const int qt = pass ? (15 - pr) : pr;  // light first, heavy second
    const int q0 = qt * 128;
    const int qg = q0 + w * 32 + l31;
    const int wq_min = q0 + w * 32, wq_max = wq_min + 31;

    // Q fragments: lane holds Q[qg][kc*16 + hi*8 + e]
    bf16x8 bq[4];
    {
      const __hip_bfloat16* qp = qkv + (rowbase + qg) * 3072 + h * 64 + hi * 8;
      bq[0] = *(const bf16x8*)(qp);
      bq[1] = *(const bf16x8*)(qp + 16);
      bq[2] = *(const bf16x8*)(qp + 32);
      bq[3] = *(const bf16x8*)(qp + 48);
    }

    const int jmax = 2 * qt + 1;

    if (pass) __syncthreads();   // pass-0 VT readers done before restaging

    // prologue: K subtile 0 into ka; V tile 0 into VT[0]
    uint4 ka0, ka1, ka2, ka3, kb0, kb1, kb2, kb3;
    ka0 = *(const uint4*)(kbyte);
    ka1 = *(const uint4*)(kbyte + 32);
    ka2 = *(const uint4*)(kbyte + 64);
    ka3 = *(const uint4*)(kbyte + 96);
    {
      const __hip_bfloat16* vp = qkv + (rowbase + lane) * 3072 + 2048 + h * 64 + w * 16;
      uint4 v0 = *(const uint4*)(vp);
      uint4 v1 = *(const uint4*)(vp + 8);
      const __hip_bfloat16* p0 = (const __hip_bfloat16*)&v0;
      const __hip_bfloat16* p1 = (const __hip_bfloat16*)&v1;
      #pragma unroll
      for (int e = 0; e < 8; ++e) {
        VT[0][(w * 16 + e) * VSTR + lane] = p0[e];
        VT[0][(w * 16 + 8 + e) * VSTR + lane] = p1[e];
      }
    }

    float mrow = NEG_BIG, plocal = 0.f;
    f32x16 o0 = {}, o1 = {};   // O^T: col q=l31, row d = dblk*32 + (r&3)+8*(r>>2)+4*hi
    int buf = 0;

    for (int j = 0; j <= jmax; ++j) {
      __syncthreads();  // VT[buf] staged; prior readers of nbuf done
      const int nbuf = buf ^ 1;
      const int j0 = j * 64;
      const bool pre = (j < jmax);
      uint4 vva, vvb;
      if (pre) {
        const __hip_bfloat16* vp = qkv + (rowbase + j0 + 64 + lane) * 3072 + 2048 + h * 64 + w * 16;
        vva = *(const uint4*)(vp);
        vvb = *(const uint4*)(vp + 8);
      }
      const __hip_bfloat16* vb0 = VT[buf] + l31 * VSTR + hi * 8;

      attn_subtile(j0, wq_min, wq_max, qg, allones, kbyte, mbrow,
                   ka0, ka1, ka2, ka3, kb0, kb1, kb2, kb3,
                   bq, vb0, hi, mrow, plocal, o0, o1);
      attn_subtile(j0 + 32, wq_min, wq_max, qg, allones, kbyte, mbrow,
                   kb0, kb1, kb2, kb3, ka0, ka1, ka2, ka3,
                   bq, vb0 + 32, hi, mrow, plocal, o0, o1);

      if (pre) {  // finish staging of nbuf (VT)
        const __hip_bfloat16* p0 = (const __hip_bfloat16*)&vva;
        const __hip_bfloat16* p1 = (const __hip_bfloat16*)&vvb;
        #pragma unroll
        for (int e = 0; e < 8; ++e) {
          VT[nbuf][(w * 16 + e) * VSTR + lane] = p0[e];
          VT[nbuf][(w * 16 + 8 + e) * VSTR + lane] = p1[e];
        }
      }
      buf = nbuf;
    }

    {  // epilogue: reduce l across hi halves, divide, store
      float l = plocal + __shfl_xor(plocal, 32);
      float linv = (l > 0.f) ? 1.f / l : 0.f;
      __hip_bfloat16* ob = outp + (rowbase + qg) * 1024 + h * 64;
      #pragma unroll
      for (int rr = 0; rr < 4; ++rr) {
        bf16x4v ov;
        ov[0] = (__bf16)(o0[rr * 4 + 0] * linv);
        ov[1] = (__bf16)(o0[rr * 4 + 1] * linv);
        ov[2] = (__bf16)(o0[rr * 4 + 2] * linv);
        ov[3] = (__bf16)(o0[rr * 4 + 3] * linv);
        *(bf16x4v*)(ob + rr * 8 + hi * 4) = ov;
        bf16x4v ow;
        ow[0] = (__bf16)(o1[rr * 4 + 0] * linv);
        ow[1] = (__bf16)(o1[rr * 4 + 1] * linv);
        ow[2] = (__bf16)(o1[rr * 4 + 2] * linv);
        ow[3] = (__bf16)(o1[rr * 4 + 3] * linv);
        *(bf16x4v*)(ob + 32 + rr * 8 + hi * 4) = ow;
      }
    }
  }
}

extern "C" void kernel_launch(void* const* d_in, const int* in_sizes, int n_in,
                              void* d_out, int out_size, void* d_ws, size_t ws_size,
                              hipStream_t stream) {
  const bool merged = (ws_size >= (80ull << 20));
  char* ws = (char*)d_ws;
  int*            flag   = (int*)ws;
  float*          bq     = (float*)(ws + 1024);
  float*          bp     = (float*)(ws + 16384);
  float*          mbias  = (float*)(ws + 32768);
  unsigned short* WqkvTu = (unsigned short*)(ws + 65536);
  unsigned short* WprojTu= (unsigned short*)(ws + 65536 + 6291456);
  char*           big    = ws + 65536 + 8388608;
  __hip_bfloat16* qkv    = (__hip_bfloat16*)big;
  // attno region doubles as xbf (x pre-converted to bf16): xbf is consumed
  // by GEMM1 before attn writes attno over it.
  char*           anx    = big + (merged ? 50331648u : 12582912u);
  __hip_bfloat16* attno  = (__hip_bfloat16*)anx;
  unsigned short* xbf    = (unsigned short*)anx;

  probe_dtype<<<1, 256, 0, stream>>>((const unsigned short*)d_in[0], flag);
  prep<<<48, 256, 0, stream>>>((const int*)d_in[1], mbias, flag,
                               d_in[3], bq, d_in[5], bp);
  transpose_conv<<<dim3(96, 32), 256, 0, stream>>>(d_in[2], WqkvTu, flag, 1024, 3072);
  transpose_conv<<<dim3(32, 32), 256, 0, stream>>>(d_in[4], WprojTu, flag, 1024, 1024);

  const int nchunk = merged ? 1 : B_;
  const int bsz = merged ? B_ : 1;
  const int Mc = bsz * S_;
  for (int c = 0; c < nchunk; ++c) {
    long long off = (long long)c * S_ * E_;
    conv_x_bf16<<<dim3((Mc * 1024) / 2048), 256, 0, stream>>>(
        d_in[0], off, xbf, flag, (Mc * 1024) / 8);
    gemm_bb<<<dim3((Mc / 128) * (3072 / 128)), 256, 0, stream>>>(
        (const __hip_bfloat16*)xbf, (const __hip_bfloat16*)WqkvTu, bq, flag, 0,
        qkv, 0, Mc, 3072, 1024);
    attn_flash<<<dim3((S_ / 256) * (bsz * H_)), 256, 0, stream>>>(
        qkv, mbias + (size_t)c * S_, flag, attno);
    gemm_bb<<<dim3((Mc / 128) * (1024 / 128)), 256, 0, stream>>>(
        attno, (const __hip_bfloat16*)WprojTu, bp, flag, 1,
        d_out, off, Mc, 1024, 1024);
  }
}

// Round 9
// 290.673 us; speedup vs baseline: 1.0629x; 1.0629x over previous
//
#include <hip/hip_runtime.h>
#include <hip/hip_bf16.h>
#include <cstdint>
#include <cstddef>

#define B_ 4
#define S_ 2048
#define E_ 1024
#define H_ 16
#define D_ 64
#define NEG_BIG (-1e30f)
#define SC2 0.18033688011112043f   /* 0.125 * log2(e) */

typedef __bf16 bf16x8 __attribute__((ext_vector_type(8)));
typedef __bf16 bf16x4v __attribute__((ext_vector_type(4)));
typedef float f32x4 __attribute__((ext_vector_type(4)));
typedef float f32x16 __attribute__((ext_vector_type(16)));

__device__ __forceinline__ void async_copy16(void* lds, const void* g) {
  __builtin_amdgcn_global_load_lds(
      (const __attribute__((address_space(1))) void*)g,
      (__attribute__((address_space(3))) void*)lds, 16, 0, 0);
}

__device__ __forceinline__ float bfu2f(unsigned short u) {
  unsigned v = ((unsigned)u) << 16;
  float f;
  __builtin_memcpy(&f, &v, 4);
  return f;
}
__device__ __forceinline__ unsigned short f2bfu(float f) {
  __hip_bfloat16 h = __float2bfloat16(f);  // RNE
  unsigned short u;
  __builtin_memcpy(&u, &h, 2);
  return u;
}
__device__ __forceinline__ unsigned pk2(float a, float b) {
  return (unsigned)f2bfu(a) | ((unsigned)f2bfu(b) << 16);
}

// swap hi 32 lanes of a with lo 32 lanes of b (v_permlane32_swap_b32)
__device__ __forceinline__ void pl32swap(unsigned& a, unsigned& b) {
#if defined(__has_builtin)
#if __has_builtin(__builtin_amdgcn_permlane32_swap)
  typedef int i32x2 __attribute__((ext_vector_type(2)));
  i32x2 r = __builtin_amdgcn_permlane32_swap((int)a, (int)b, false, false);
  a = (unsigned)r[0];
  b = (unsigned)r[1];
  return;
#else
  asm("v_permlane32_swap_b32 %0, %1" : "+v"(a), "+v"(b));
  return;
#endif
#else
  asm("v_permlane32_swap_b32 %0, %1" : "+v"(a), "+v"(b));
#endif
}

// ---------------- dtype probe (proven) ----------------
__global__ __launch_bounds__(256) void probe_dtype(
    const unsigned short* __restrict__ xr, int* __restrict__ flagp) {
  __shared__ int cnt;
  if (threadIdx.x == 0) cnt = 0;
  __syncthreads();
  int bad = 0;
  for (int i = 0; i < 32; ++i) {
    unsigned short u = xr[(threadIdx.x * 32 + i) * 2];
    int e = (u >> 7) & 0xFF;
    if (e == 0xFF || e >= 0x90 || (e != 0 && e <= 0x60)) bad++;
  }
  atomicAdd(&cnt, bad);
  __syncthreads();
  if (threadIdx.x == 0) {
    flagp[0] = (cnt > 512) ? 0 : 1;  // 0=fp32, 1=bf16
    flagp[1] = 1;                    // all-ones-mask flag, cleared by megaprep
  }
}

// transpose tile helper: out_bf16[C][R] = in[R][C], one 32x32 tile
__device__ __forceinline__ void transpose_tile(
    const void* __restrict__ in, unsigned short* __restrict__ out,
    int flag, int R, int C, int bx, int by, int tid) {
  __shared__ unsigned short t[32][33];
  const int c0 = bx * 32, r0 = by * 32;
  const int lc = tid & 31, lr = tid >> 5;
  #pragma unroll
  for (int i = 0; i < 4; ++i) {
    int r = lr + i * 8;
    size_t idx = (size_t)(r0 + r) * C + c0 + lc;
    t[r][lc] = (flag == 0) ? f2bfu(((const float*)in)[idx])
                           : ((const unsigned short*)in)[idx];
  }
  __syncthreads();
  #pragma unroll
  for (int i = 0; i < 4; ++i) {
    int r = lr + i * 8;
    out[(size_t)(c0 + r) * R + r0 + lc] = t[lc][r];
  }
}

// -------- fused preamble: mask-bias + bias conversions + both weight
// transposes + x->bf16 conversion, all in ONE dispatch (branch on
// blockIdx, uniform per block).  Replaces 4 serial small kernels + gaps.
__global__ __launch_bounds__(256) void megaprep(
    const int* __restrict__ am, float* __restrict__ mb,
    int* __restrict__ flagp,
    const void* __restrict__ bq_in, float* __restrict__ bq,
    const void* __restrict__ bp_in, float* __restrict__ bp,
    const void* __restrict__ Wqkv_in, unsigned short* __restrict__ WqkvT,
    const void* __restrict__ Wproj_in, unsigned short* __restrict__ WprojT,
    const void* __restrict__ x_in, unsigned short* __restrict__ xbf,
    int n8) {
  const int flag = flagp[0];
  const int b = blockIdx.x;
  const int tid = threadIdx.x;
  if (b < 32) {                       // pad mask -> additive bias + allones
    int i = b * 256 + tid;
    int a = am[i];
    mb[i] = a ? 0.f : NEG_BIG;
    if (a == 0) atomicAnd(flagp + 1, 0);
  } else if (b < 44) {                // bias_qkv -> f32 (3072)
    int j = (b - 32) * 256 + tid;
    bq[j] = (flag == 0) ? ((const float*)bq_in)[j]
                        : bfu2f(((const unsigned short*)bq_in)[j]);
  } else if (b < 48) {                // bias_proj -> f32 (1024)
    int j = (b - 44) * 256 + tid;
    bp[j] = (flag == 0) ? ((const float*)bp_in)[j]
                        : bfu2f(((const unsigned short*)bp_in)[j]);
  } else if (b < 3120) {              // Wqkv^T: [1024][3072] -> [3072][1024]
    int t = b - 48;
    transpose_tile(Wqkv_in, WqkvT, flag, 1024, 3072, t % 96, t / 96, tid);
  } else if (b < 4144) {              // Wproj^T: [1024][1024] -> [1024][1024]
    int t = b - 3120;
    transpose_tile(Wproj_in, WprojT, flag, 1024, 1024, t % 32, t / 32, tid);
  } else {                            // x -> bf16, 8 elems/thread
    int i = (b - 4144) * 256 + tid;
    if (i >= n8) return;
    if (flag == 0) {
      const float* p = (const float*)x_in + (size_t)i * 8;
      float4 a = *(const float4*)p;
      float4 c = *(const float4*)(p + 4);
      uint4 o = make_uint4(pk2(a.x, a.y), pk2(a.z, a.w), pk2(c.x, c.y), pk2(c.z, c.w));
      *(uint4*)(xbf + (size_t)i * 8) = o;
    } else {
      const unsigned short* p = (const unsigned short*)x_in + (size_t)i * 8;
      *(uint4*)(xbf + (size_t)i * 8) = *(const uint4*)p;
    }
  }
}

// x (fp32|bf16) -> bf16 (non-merged fallback path only)
__global__ __launch_bounds__(256) void conv_x_bf16(
    const void* __restrict__ in, long long off,
    unsigned short* __restrict__ out,
    const int* __restrict__ flagp, int n8) {
  int i = blockIdx.x * 256 + threadIdx.x;
  if (i >= n8) return;
  if (*flagp == 0) {
    const float* p = (const float*)in + off + (size_t)i * 8;
    float4 a = *(const float4*)p;
    float4 b = *(const float4*)(p + 4);
    uint4 o = make_uint4(pk2(a.x, a.y), pk2(a.z, a.w), pk2(b.x, b.y), pk2(b.z, b.w));
    *(uint4*)(out + (size_t)i * 8) = o;
  } else {
    const unsigned short* p = (const unsigned short*)in + off + (size_t)i * 8;
    *(uint4*)(out + (size_t)i * 8) = *(const uint4*)p;
  }
}

// -------- unified bf16 GEMM (R6-proven): C = A @ Bt^T + bias -------------
// 128x128 tile, 256 threads, BK=64 (32 MFMA per barrier pair), async
// global->LDS, 8-chunk XOR swizzle (ch ^ row&7), XCD-chunked 1D grid.
// bf16 out: staged through dead 32KB LDS, coalesced dwordx4 writes.
// fp32 out: direct scalar stores.  (R7's 256x128 dbuf variant was NULL:
// 96KB LDS -> 1 block/CU traded away the TLP that was hiding staging.)
__global__ __launch_bounds__(256) void gemm_bb(
    const __hip_bfloat16* __restrict__ A,
    const __hip_bfloat16* __restrict__ Bt,
    const float* __restrict__ bias,
    const int* __restrict__ flagp, int outmode,
    void* __restrict__ Cv, long long coff,
    int M, int N, int K) {
  __shared__ __align__(16) __hip_bfloat16 SH[2][128 * 64];
  __hip_bfloat16* As = SH[0];
  __hip_bfloat16* Bs = SH[1];
  const int flag = *flagp;
  const int tid = threadIdx.x;
  const int lin = blockIdx.x;
  const int mtiles = M >> 7;
  const int mloc = mtiles >> 3;                 // m-tiles per XCD (pow2)
  const int msh = 31 - __builtin_clz(mloc);
  const int xcd = lin & 7, idx = lin >> 3;
  const int m0 = (xcd * mloc + (idx & (mloc - 1))) << 7;
  const int n0 = (idx >> msh) << 7;
  const int w = tid >> 6, lane = tid & 63;
  const int wm = (w & 1) * 64, wn = (w >> 1) * 64;
  const int lm = lane & 15, kg = lane >> 4;

  f32x4 acc[4][4] = {};

  for (int k0 = 0; k0 < K; k0 += 64) {
    __syncthreads();   // readers of LDS done
    #pragma unroll
    for (int c = 0; c < 4; ++c) {
      int o = tid * 16 + c * 4096;
      int row = o >> 7, chp = (o >> 4) & 7;
      int gch = chp ^ (row & 7);
      async_copy16((char*)As + o, (const char*)(A + (size_t)(m0 + row) * K + k0 + gch * 8));
      async_copy16((char*)Bs + o, (const char*)(Bt + (size_t)(n0 + row) * K + k0 + gch * 8));
    }
    __syncthreads();   // staging landed (compiler drains vmcnt before barrier)
    #pragma unroll
    for (int kk = 0; kk < 2; ++kk) {
      bf16x8 af[4], bff[4];
      #pragma unroll
      for (int t = 0; t < 4; ++t) {
        int rt = wm + t * 16 + lm;
        int ch = (kk * 4 + kg) ^ (rt & 7);
        af[t] = *(const bf16x8*)(As + rt * 64 + ch * 8);
        int rb = wn + t * 16 + lm;
        int chb = (kk * 4 + kg) ^ (rb & 7);
        bff[t] = *(const bf16x8*)(Bs + rb * 64 + chb * 8);
      }
      #pragma unroll
      for (int tm = 0; tm < 4; ++tm)
        #pragma unroll
        for (int tn = 0; tn < 4; ++tn)
          acc[tm][tn] = __builtin_amdgcn_mfma_f32_16x16x32_bf16(af[tm], bff[tn], acc[tm][tn], 0, 0, 0);
    }
  }

  const bool f32out = (outmode != 0 && flag == 0);
  if (f32out) {
    // direct scalar stores (proven) -- f32 tile doesn't fit staged in LDS
    for (int tn = 0; tn < 4; ++tn) {
      int col = n0 + wn + tn * 16 + lm;
      float bv = bias[col];
      for (int tm = 0; tm < 4; ++tm) {
        int rbase = m0 + wm + tm * 16 + kg * 4;
        for (int r = 0; r < 4; ++r)
          ((float*)Cv)[(size_t)coff + (size_t)(rbase + r) * N + col] =
              acc[tm][tn][r] + bv;
      }
    }
  } else {
    // bf16: LDS-staged coalesced writes, two 64-row passes (stride 136>127)
    for (int hp = 0; hp < 2; ++hp) {
      __syncthreads();   // prior LDS readers done
      if (wm == hp * 64) {
        __hip_bfloat16* Cs16 = (__hip_bfloat16*)SH;  // stride 136 (272B)
        #pragma unroll
        for (int tn = 0; tn < 4; ++tn) {
          int col = wn + tn * 16 + lm;
          float bv = bias[n0 + col];
          #pragma unroll
          for (int tm = 0; tm < 4; ++tm)
            #pragma unroll
            for (int r = 0; r < 4; ++r)
              Cs16[(tm * 16 + kg * 4 + r) * 136 + col] =
                  __float2bfloat16(acc[tm][tn][r] + bv);
        }
      }
      __syncthreads();
      const __hip_bfloat16* Cs16 = (const __hip_bfloat16*)SH;
      unsigned short* outp = (unsigned short*)Cv + coff;
      #pragma unroll
      for (int rd = 0; rd < 4; ++rd) {
        int chunk = rd * 256 + tid;             // 0..1023
        int row = chunk >> 4, cch = chunk & 15;
        uint4 v = *(const uint4*)(Cs16 + row * 136 + cch * 8);
        *(uint4*)(outp + (size_t)(m0 + hp * 64 + row) * N + n0 + cch * 8) = v;
      }
    }
  }
}

// -------- causal flash attention v5 (proven R6 config, 108.8us) ------------
// 256 threads (4 waves), 128 q/block (32 q/wave), 32-key subtiles.
// K fetched DIRECTLY global->VGPR as MFMA A-fragments, software-pipelined
// one subtile ahead (ka/kb parity) -- no K LDS, no K barrier coupling.
// Only V goes through LDS (transposed, double-buffered, 1 barrier/tile).
// XCD-chunked block swizzle keeps each (b,h)'s K/V panels L2-hot.
// NOTE (R3): 128-thread (128,4) variant spilled (~470MB scratch, 2.5x slower).
// NOTE (R8): paired q-tiles (grid 512 = 8 waves/CU) regressed +8us -- this
// kernel lives on TLP; keep grid 1024 = 16 waves/CU.
#define VSTR 72
__device__ __forceinline__ void attn_subtile(
    int j0s, int wq_min, int wq_max, int qg, int allones,
    const char* kbyte, const float* mbrow,
    uint4& kc0, uint4& kc1, uint4& kc2, uint4& kc3,
    uint4& kn0, uint4& kn1, uint4& kn2, uint4& kn3,
    const bf16x8* bq, const __hip_bfloat16* VTb, int hi,
    float& mrow, float& plocal, f32x16& o0, f32x16& o1) {
  if (j0s > wq_max) return;
  {  // prefetch next subtile's K fragments (registers)
    const int jn = j0s + 32;
    if (jn <= wq_max) {
      const char* kp = kbyte + (size_t)jn * 6144;
      kn0 = *(const uint4*)(kp);
      kn1 = *(const uint4*)(kp + 32);
      kn2 = *(const uint4*)(kp + 64);
      kn3 = *(const uint4*)(kp + 96);
    }
  }
  bf16x8 a0, a1, a2, a3;
  __builtin_memcpy(&a0, &kc0, 16);
  __builtin_memcpy(&a1, &kc1, 16);
  __builtin_memcpy(&a2, &kc2, 16);
  __builtin_memcpy(&a3, &kc3, 16);

  // ---- S^T = K · Q^T ----
  f32x16 sacc = {};
  __builtin_amdgcn_s_setprio(1);
  sacc = __builtin_amdgcn_mfma_f32_32x32x16_bf16(a0, bq[0], sacc, 0, 0, 0);
  sacc = __builtin_amdgcn_mfma_f32_32x32x16_bf16(a1, bq[1], sacc, 0, 0, 0);
  sacc = __builtin_amdgcn_mfma_f32_32x32x16_bf16(a2, bq[2], sacc, 0, 0, 0);
  sacc = __builtin_amdgcn_mfma_f32_32x32x16_bf16(a3, bq[3], sacc, 0, 0, 0);
  __builtin_amdgcn_s_setprio(0);

  // ---- mask + max ----
  float mt = NEG_BIG;
  const bool needc = (j0s + 31 > wq_min);
  if (allones) {
    if (needc) {
      #pragma unroll
      for (int r = 0; r < 16; ++r) {
        int key = j0s + (r & 3) + 8 * (r >> 2) + 4 * hi;
        float v = (key <= qg) ? sacc[r] : NEG_BIG;
        sacc[r] = v;
        mt = fmaxf(mt, v);
      }
    } else {
      #pragma unroll
      for (int r = 0; r < 16; ++r) mt = fmaxf(mt, sacc[r]);
    }
    mt *= SC2;  // scores stay raw; scale folded into exp fma
  } else {
    #pragma unroll
    for (int rr = 0; rr < 4; ++rr) {
      float4 mb4 = *(const float4*)(mbrow + j0s + rr * 8 + hi * 4);
      const float* mp = (const float*)&mb4;
      #pragma unroll
      for (int i = 0; i < 4; ++i) {
        int r = rr * 4 + i;
        int key = j0s + i + 8 * rr + 4 * hi;
        float v = fmaf(sacc[r], SC2, mp[i]);
        if (needc) v = (key <= qg) ? v : NEG_BIG;
        sacc[r] = v;
        mt = fmaxf(mt, v);
      }
    }
  }
  mt = fmaxf(mt, __shfl_xor(mt, 32));

  // ---- defer-max rescale (THR=8, log2 domain) ----
  if (!__all(mt <= mrow + 8.f)) {
    float mn = fmaxf(mrow, mt);
    float a = __builtin_exp2f(mrow - mn);
    plocal *= a;
    #pragma unroll
    for (int r = 0; r < 16; ++r) { o0[r] *= a; o1[r] *= a; }
    mrow = mn;
  }

  // ---- exp + pack ----
  const float sfac = allones ? SC2 : 1.0f;
  float psl = 0.f;
  unsigned pk[8];
  #pragma unroll
  for (int r2 = 0; r2 < 8; ++r2) {
    float p0 = __builtin_exp2f(fmaf(sacc[2 * r2],     sfac, -mrow));
    float p1 = __builtin_exp2f(fmaf(sacc[2 * r2 + 1], sfac, -mrow));
    psl += p0 + p1;
    pk[r2] = pk2(p0, p1);
  }
  plocal += psl;

  // ---- in-register P exchange ----
  pl32swap(pk[0], pk[2]);
  pl32swap(pk[1], pk[3]);
  pl32swap(pk[4], pk[6]);
  pl32swap(pk[5], pk[7]);

  // ---- O^T += V^T · P ----
  __builtin_amdgcn_s_setprio(1);
  #pragma unroll
  for (int ks = 0; ks < 2; ++ks) {
    uint4 t = make_uint4(pk[ks * 4 + 0], pk[ks * 4 + 1],
                         pk[ks * 4 + 2], pk[ks * 4 + 3]);
    bf16x8 bp;
    __builtin_memcpy(&bp, &t, 16);
    bf16x8 av0 = *(const bf16x8*)(VTb + ks * 16);
    bf16x8 av1 = *(const bf16x8*)(VTb + 32 * VSTR + ks * 16);
    o0 = __builtin_amdgcn_mfma_f32_32x32x16_bf16(av0, bp, o0, 0, 0, 0);
    o1 = __builtin_amdgcn_mfma_f32_32x32x16_bf16(av1, bp, o1, 0, 0, 0);
  }
  __builtin_amdgcn_s_setprio(0);
}

__global__ __launch_bounds__(256, 3) void attn_flash(
    const __hip_bfloat16* __restrict__ qkv,  // [bsz*S][3072]
    const float* __restrict__ mbias,         // [bsz*S] 0 / -1e30
    const int* __restrict__ flags,           // flags[1]: mask all-ones
    __hip_bfloat16* __restrict__ outp) {     // [bsz*S][1024]
  __shared__ __align__(16) __hip_bfloat16 VT[2][64 * VSTR]; // [d][key]

  const int tid = threadIdx.x;
  // XCD-chunked swizzle: XCD k owns bh in [k*bhloc,(k+1)*bhloc), all q-tiles;
  // within XCD, heavy q-tiles (large qt) dispatched first (LPT).
  const int lin = blockIdx.x;
  const int nbh = gridDim.x >> 4;          // 16 q-blocks of 128 rows
  const int bhloc = nbh >> 3;
  const int bsh = 31 - __builtin_clz(bhloc);
  const int xcd = lin & 7, idx = lin >> 3;
  const int bh = xcd * bhloc + (idx & (bhloc - 1));
  const int bx = idx >> bsh;
  const int qt = 15 - bx;                  // LPT: heavy first
  const int b = bh >> 4, h = bh & 15;
  const int q0 = qt * 128;
  const size_t rowbase = (size_t)b * S_;
  const int w = tid >> 6, lane = tid & 63;
  const int l31 = lane & 31, hi = lane >> 5;
  const int qg = q0 + w * 32 + l31;
  const int wq_min = q0 + w * 32, wq_max = wq_min + 31;
  const int allones = flags[1];
  const float* mbrow = mbias + rowbase;

  // per-lane K base: row l31, d-offset hi*8 (fragment kc at +kc*32B)
  const char* kbyte = (const char*)(qkv + (rowbase + l31) * 3072 + 1024 + h * 64 + hi * 8);

  // Q fragments: lane holds Q[qg][kc*16 + hi*8 + e]
  bf16x8 bq[4];
  {
    const __hip_bfloat16* qp = qkv + (rowbase + qg) * 3072 + h * 64 + hi * 8;
    bq[0] = *(const bf16x8*)(qp);
    bq[1] = *(const bf16x8*)(qp + 16);
    bq[2] = *(const bf16x8*)(qp + 32);
    bq[3] = *(const bf16x8*)(qp + 48);
  }

  const int jmax = 2 * qt + 1;

  // prologue: K subtile 0 into ka; V tile 0 into VT[0]
  uint4 ka0, ka1, ka2, ka3, kb0, kb1, kb2, kb3;
  ka0 = *(const uint4*)(kbyte);
  ka1 = *(const uint4*)(kbyte + 32);
  ka2 = *(const uint4*)(kbyte + 64);
  ka3 = *(const uint4*)(kbyte + 96);
  {
    const __hip_bfloat16* vp = qkv + (rowbase + lane) * 3072 + 2048 + h * 64 + w * 16;
    uint4 v0 = *(const uint4*)(vp);
    uint4 v1 = *(const uint4*)(vp + 8);
    const __hip_bfloat16* p0 = (const __hip_bfloat16*)&v0;
    const __hip_bfloat16* p1 = (const __hip_bfloat16*)&v1;
    #pragma unroll
    for (int e = 0; e < 8; ++e) {
      VT[0][(w * 16 + e) * VSTR + lane] = p0[e];
      VT[0][(w * 16 + 8 + e) * VSTR + lane] = p1[e];
    }
  }

  float mrow = NEG_BIG, plocal = 0.f;
  f32x16 o0 = {}, o1 = {};   // O^T: col q=l31, row d = dblk*32 + (r&3)+8*(r>>2)+4*hi
  int buf = 0;

  for (int j = 0; j <= jmax; ++j) {
    __syncthreads();  // VT[buf] staged; prior readers of nbuf done
    const int nbuf = buf ^ 1;
    const int j0 = j * 64;
    const bool pre = (j < jmax);
    uint4 vva, vvb;
    if (pre) {
      const __hip_bfloat16* vp = qkv + (rowbase + j0 + 64 + lane) * 3072 + 2048 + h * 64 + w * 16;
      vva = *(const uint4*)(vp);
      vvb = *(const uint4*)(vp + 8);
    }
    const __hip_bfloat16* vb0 = VT[buf] + l31 * VSTR + hi * 8;

    attn_subtile(j0, wq_min, wq_max, qg, allones, kbyte, mbrow,
                 ka0, ka1, ka2, ka3, kb0, kb1, kb2, kb3,
                 bq, vb0, hi, mrow, plocal, o0, o1);
    attn_subtile(j0 + 32, wq_min, wq_max, qg, allones, kbyte, mbrow,
                 kb0, kb1, kb2, kb3, ka0, ka1, ka2, ka3,
                 bq, vb0 + 32, hi, mrow, plocal, o0, o1);

    if (pre) {  // finish staging of nbuf (VT)
      const __hip_bfloat16* p0 = (const __hip_bfloat16*)&vva;
      const __hip_bfloat16* p1 = (const __hip_bfloat16*)&vvb;
      #pragma unroll
      for (int e = 0; e < 8; ++e) {
        VT[nbuf][(w * 16 + e) * VSTR + lane] = p0[e];
        VT[nbuf][(w * 16 + 8 + e) * VSTR + lane] = p1[e];
      }
    }
    buf = nbuf;
  }

  {  // epilogue: reduce l across hi halves, divide, store
    float l = plocal + __shfl_xor(plocal, 32);
    float linv = (l > 0.f) ? 1.f / l : 0.f;
    __hip_bfloat16* ob = outp + (rowbase + qg) * 1024 + h * 64;
    #pragma unroll
    for (int rr = 0; rr < 4; ++rr) {
      bf16x4v ov;
      ov[0] = (__bf16)(o0[rr * 4 + 0] * linv);
      ov[1] = (__bf16)(o0[rr * 4 + 1] * linv);
      ov[2] = (__bf16)(o0[rr * 4 + 2] * linv);
      ov[3] = (__bf16)(o0[rr * 4 + 3] * linv);
      *(bf16x4v*)(ob + rr * 8 + hi * 4) = ov;
      bf16x4v ow;
      ow[0] = (__bf16)(o1[rr * 4 + 0] * linv);
      ow[1] = (__bf16)(o1[rr * 4 + 1] * linv);
      ow[2] = (__bf16)(o1[rr * 4 + 2] * linv);
      ow[3] = (__bf16)(o1[rr * 4 + 3] * linv);
      *(bf16x4v*)(ob + 32 + rr * 8 + hi * 4) = ow;
    }
  }
}

extern "C" void kernel_launch(void* const* d_in, const int* in_sizes, int n_in,
                              void* d_out, int out_size, void* d_ws, size_t ws_size,
                              hipStream_t stream) {
  const bool merged = (ws_size >= (80ull << 20));
  char* ws = (char*)d_ws;
  int*            flag   = (int*)ws;
  float*          bq     = (float*)(ws + 1024);
  float*          bp     = (float*)(ws + 16384);
  float*          mbias  = (float*)(ws + 32768);
  unsigned short* WqkvTu = (unsigned short*)(ws + 65536);
  unsigned short* WprojTu= (unsigned short*)(ws + 65536 + 6291456);
  char*           big    = ws + 65536 + 8388608;
  __hip_bfloat16* qkv    = (__hip_bfloat16*)big;
  // attno region doubles as xbf (x pre-converted to bf16): xbf is consumed
  // by GEMM1 before attn writes attno over it.
  char*           anx    = big + (merged ? 50331648u : 12582912u);
  __hip_bfloat16* attno  = (__hip_bfloat16*)anx;
  unsigned short* xbf    = (unsigned short*)anx;

  probe_dtype<<<1, 256, 0, stream>>>((const unsigned short*)d_in[0], flag);

  const int nconv8 = merged ? (B_ * S_ * E_ / 8) : 0;     // 1,048,576
  const int mpgrid = 4144 + (merged ? nconv8 / 256 : 0);  // 8240 merged
  megaprep<<<mpgrid, 256, 0, stream>>>(
      (const int*)d_in[1], mbias, flag,
      d_in[3], bq, d_in[5], bp,
      d_in[2], WqkvTu, d_in[4], WprojTu,
      d_in[0], xbf, nconv8);

  const int nchunk = merged ? 1 : B_;
  const int bsz = merged ? B_ : 1;
  const int Mc = bsz * S_;
  for (int c = 0; c < nchunk; ++c) {
    long long off = (long long)c * S_ * E_;
    if (!merged)
      conv_x_bf16<<<dim3((Mc * 1024) / 2048), 256, 0, stream>>>(
          d_in[0], off, xbf, flag, (Mc * 1024) / 8);
    gemm_bb<<<dim3((Mc / 128) * (3072 / 128)), 256, 0, stream>>>(
        (const __hip_bfloat16*)xbf, (const __hip_bfloat16*)WqkvTu, bq, flag, 0,
        qkv, 0, Mc, 3072, 1024);
    attn_flash<<<dim3((S_ / 128) * (bsz * H_)), 256, 0, stream>>>(
        qkv, mbias + (size_t)c * S_, flag, attno);
    gemm_bb<<<dim3((Mc / 128) * (1024 / 128)), 256, 0, stream>>>(
        attno, (const __hip_bfloat16*)WprojTu, bp, flag, 1,
        d_out, off, Mc, 1024, 1024);
  }
}